// Round 11
// baseline (944.638 us; speedup 1.0000x reference)
//
#include <hip/hip_runtime.h>

#define S 128
#define NEGF (-1e30f)
#define MAXB 16
#define NT 1024
#define STAGE_SZ 8064     // max over wn of 2*(S-wn-1)*((wn-1)|1)  (wn=63)
#define PKB 700000        // per-batch packed sib floats (>= 698250 exact)

// Static device workspace (d_ws proved unreliable in rounds 0-2).
__device__ float g_ssw[MAXB * S * S];        // sibling spans, [b][width][start]
__device__ float g_spk[(size_t)MAXB * PKB];  // packed sib, [b][wn][typ][k-1][i]
__device__ float g_logZ[MAXB];
__device__ float g_partials[512];

// Rotation swizzle: column reads (r varies, c fixed) hit bank (c+r)%32 ->
// conflict-free; row reads remain a per-row permutation -> also free.
#define SC(r, c) sc[r][((c) + (r)) & 127]

__device__ __forceinline__ bool mask_at(const unsigned char* m, int i, bool by) {
  return by ? (m[i] != 0) : (((const int*)m)[i] != 0);
}

// global -> LDS DMA, 4B/lane: dest = wave-uniform base + lane*4 (r6-r10 verified).
__device__ __forceinline__ void gload_lds4(const float* g, float* l) {
  __builtin_amdgcn_global_load_lds(
      (const __attribute__((address_space(1))) unsigned int*)g,
      (__attribute__((address_space(3))) unsigned int*)l, 4, 0, 0);
}

// Online-lse pieces (r8/r10-verified). Finite NEGF sentinel => no NaN.
__device__ __forceinline__ void upd(float& m, float& s, float v) {
  float mn = fmaxf(m, v);
  s = s * __expf(m - mn) + __expf(v - mn);
  m = mn;
}
__device__ __forceinline__ void fold(float& m0, float& s0, float m1, float s1) {
  float mn = fmaxf(m0, m1);
  s0 = s0 * __expf(m0 - mn) + s1 * __expf(m1 - mn);
  m0 = mn;
}
template <int CTRL>
__device__ __forceinline__ float dpp_f(float x) {
  int i = __float_as_int(x);
  return __int_as_float(__builtin_amdgcn_update_dpp(i, i, CTRL, 0xF, 0xF, false));
}
// Cross-lane (m,s) fold over p=2^lp lane-aligned groups (r5/r9/r10-verified
// ctrls): xor1(0xB1), xor2(0x4E), mirror8(0x141)~xor4, mirror16(0x140)~xor8.
__device__ __forceinline__ void xfold(float& m, float& s, int lp) {
  if (lp >= 1) { float mo = dpp_f<0xB1>(m),  so = dpp_f<0xB1>(s);  fold(m, s, mo, so); }
  if (lp >= 2) { float mo = dpp_f<0x4E>(m),  so = dpp_f<0x4E>(s);  fold(m, s, mo, so); }
  if (lp >= 3) { float mo = dpp_f<0x141>(m), so = dpp_f<0x141>(s); fold(m, s, mo, so); }
  if (lp >= 4) { float mo = dpp_f<0x140>(m), so = dpp_f<0x140>(s); fold(m, s, mo, so); }
}
template <typename F>
__device__ __forceinline__ float lse_run(F val, int i0, int n,
                                         float base, bool has_base, int lp) {
  float m0 = has_base ? base : NEGF, s0 = has_base ? 1.f : 0.f;
  float m1 = NEGF, s1 = 0.f, m2 = NEGF, s2 = 0.f, m3 = NEGF, s3 = 0.f;
  int i = i0;
  const int ie = i0 + n;
#pragma unroll 2
  for (; i + 4 <= ie; i += 4) {
    upd(m0, s0, val(i));
    upd(m1, s1, val(i + 1));
    upd(m2, s2, val(i + 2));
    upd(m3, s3, val(i + 3));
  }
  for (; i < ie; ++i) upd(m0, s0, val(i));
  fold(m0, s0, m1, s1); fold(m2, s2, m3, s3); fold(m0, s0, m2, s2);
  xfold(m0, s0, lp);
  return __logf(s0) + m0;
}
// Families are 512 threads wide: p = 512 / next_pow2(nk), capped at 16 (DPP).
__device__ __forceinline__ int lp_for(int nk) {
  return (nk <= 32) ? 4 : (nk <= 64) ? 3 : 2;
}

// One-time repack of s_sib into the per-width stage layout (all 256 CUs):
// dst[b][OFF(wn) + (typ*(nk2-1) + (k-1))*rlP + i] = sib[b][dep][head][k+1+i]
__global__ __launch_bounds__(256) void pack_kernel(const float* __restrict__ sib) {
  const int wn = 2 + (blockIdx.x % 126);
  const int b = blockIdx.x / 126;
  const int nk2 = S - wn;
  const int rows1 = nk2 - 1;
  if (rows1 <= 0) return;
  const int rowlen = wn - 1;
  const int rlP = rowlen | 1;
  int off = 0;
  for (int v = 2; v < wn; ++v) off += 2 * (S - v - 1) * ((v - 1) | 1);
  const float* SBraw = sib + (size_t)b * S * S * S;   // [dep][head][sib]
  float* dst = g_spk + (size_t)b * PKB + off;
  const int lane5 = threadIdx.x & 31;
  const int R = 2 * rows1;
  for (int r = (threadIdx.x >> 5); r < R; r += 8) {
    const int typ = (r >= rows1) ? 1 : 0;
    const int kr = (r - typ * rows1) + 1;
    const int kw2 = kr + wn;
    const size_t srcoff = (typ == 0)
        ? ((size_t)(kw2 * S + kr) * S + (kr + 1))    // ir: sib[dep=kw][head=k][x]
        : ((size_t)(kr * S + kw2) * S + (kr + 1));   // il: sib[dep=k][head=kw][x]
    const float* src = SBraw + srcoff;
    float* d = dst + r * rlP;
    for (int i = lane5; i < rowlen; i += 32) d[i] = src[i];
  }
}

// One block (1024 thr = 16 waves) per batch element. Per width w (3 barriers):
//   ph1: ir (fam 0 = tid<512) || il (fam 1), p-lane-split online lse
//   B1; linear DMA stage(w+1) from g_spk
//   ph2: cl || cr
//   B2 (drains DMA); slot3: slr(w+1) (fam0) || enrich stage(w+1) += SSW (fam1,
//   2-32 threads per row, balanced chunks); B3
__global__ __launch_bounds__(NT) void dp_kernel(
    const float* __restrict__ arc,          // [B,S,S] s_arc[b,dep,head]
    const unsigned char* __restrict__ mask) // [B,S]
{
  __shared__ float si[S][S];
  __shared__ float sc[S][S];
  __shared__ float stage[STAGE_SZ];
  __shared__ int len_sh, cnt0_sh;

  const int b = blockIdx.x;
  const int tid = threadIdx.x;
  const float* arc_b = arc + (size_t)b * S * S;      // arc_b[dep*S+head]
  const float* spk_b = g_spk + (size_t)b * PKB;
  float* ssw = g_ssw + (size_t)b * S * S;

  if (tid == 0) { len_sh = 0; cnt0_sh = 0; }
  __syncthreads();
  if (tid < S && mask[tid] != 0) atomicAdd(&cnt0_sh, 1);  // byte-interp of row 0
  for (int i = tid; i < S * S; i += NT) {
    (&si[0][0])[i] = NEGF;
    (&sc[0][0])[i] = NEGF;
  }
  __syncthreads();
  const bool bytes = (cnt0_sh >= 64);  // bool bytes: ~127 nonzero; int32: ~31
  if (tid < S) {
    SC(tid, tid) = 0.0f;               // width-0 complete spans
    if (mask_at(mask, b * S + tid, bytes)) atomicAdd(&len_sh, 1);
  }
  if (tid >= 1 && tid < S - 1) ssw[S + tid] = 0.0f;  // S(k,k+1) = 0 bootstrap
  __syncthreads();
  const int len = min(len_sh, S - 1);
  if (tid == 0) g_logZ[b] = 0.0f;      // len==0 fallback

  const int fam = tid >> 9;            // 0 / 1 (wave-aligned at 512)
  const int floc = tid & 511;
  int spk_off = 0;                     // running OFF(wn), wn = w+1

  for (int w = 1; w < S; ++w) {
    const int nk = S - w, n1 = w - 1;
    const int rlP = n1 | 1;
    const int lp = lp_for(nk);
    const int p = 1 << lp;
    const int q = floc & (p - 1);
    const int k = floc >> lp;
    const int kw = k + w;

    // ================= phase 1: ir (fam 0) || il (fam 1) =================
    if (k < nk) {
      float bm, arcv;
      const float *pa, *pt;
      if (fam == 0) {        // I(k -> kw): base j=0; siblings x=k+1..kw-1
        bm = SC(k, k) + SC(kw, k + 1);
        arcv = arc_b[kw * S + k];
        pa = &si[k][k + 1];
        pt = &stage[(k >= 1 ? k - 1 : 0) * rlP];
      } else {               // I(kw -> k): base j=w-1; siblings x=k+1..kw-1
        bm = (k == 0) ? 0.0f : (SC(kw, kw) + SC(k, kw - 1));
        arcv = arc_b[k * S + kw];
        pa = &si[kw][k + 1];
        pt = &stage[((nk - 1) + (k >= 1 ? k - 1 : 0)) * rlP];
      }
      int i0 = 0, ntrip = 0;
      if (k >= 1 && n1 > 0) {
        const int ch = n1 >> lp;
        i0 = q * ch;
        ntrip = ((q == p - 1) ? n1 : i0 + ch) - i0;
      }
      auto val = [&](int i) { return pa[i] + pt[i]; };
      float r = lse_run(val, i0, ntrip, bm, q == 0, lp) + arcv;
      if (q == 0) {
        if (fam == 0) si[k][kw] = r; else si[kw][k] = r;
      }
    }
    __syncthreads();   // B1: si(w) final; stage(w) dead

    // ===== linear DMA: packed sib block for width w+1 (drains at B2) =====
    const int wn = w + 1;
    if (wn < S) {
      const int rows1n = S - wn - 1;
      const int T = 2 * rows1n * ((wn - 1) | 1);
      const float* src = spk_b + spk_off;
      const int wv = tid >> 6, l = tid & 63;
      for (int c = wv; c * 64 < T; c += 16) {
        const int e = c * 64 + l;
        if (e < T) gload_lds4(src + e, &stage[c * 64]);
      }
    }

    // ================= phase 2: cl (fam 0) || cr (fam 1) =================
    if (k < nk) {
      const int ch = w >> lp;
      const int i0 = q * ch;
      const int ntrip = ((q == p - 1) ? w : i0 + ch) - i0;
      if (fam == 0) {        // cl: C(kw->k) over x=0..w-1: sc[k+x][k]+si[kw][k+x]
        const float* pB = &si[kw][k];
        auto val = [&](int i) { return SC(k + i, k) + pB[i]; };
        float r = lse_run(val, i0, ntrip, NEGF, false, lp);
        if (q == 0) SC(kw, k) = r;
      } else {               // cr: C(k->kw) over y=1..w: si[k][k+y]+sc[k+y][kw]
        const float* pA = &si[k][k + 1];
        auto val = [&](int i) { return pA[i] + SC(k + 1 + i, kw); };
        float r = lse_run(val, i0, ntrip, NEGF, false, lp);
        if (q == 0) {
          if (k == 0) {
            // single-root kill: C(0->w) survives only at w == len
            if (w == len) g_logZ[b] = r;
            SC(0, w) = (w == len) ? r : NEGF;
          } else {
            SC(k, kw) = r;
          }
        }
      }
    }
    __syncthreads();   // B2: sc(w) final; DMA(w+1) landed

    // ==== slot3: slr S(*,*+wn) (fam 0) || enrich stage(wn) += SSW (fam 1) ====
    if (wn < S) {
      const int nk3 = S - wn;
      if (fam == 0) {        // slr(wn): k3 in [1, nk3); reads sc widths <= w
        const int lp3 = lp_for(nk3);
        const int p3 = 1 << lp3;
        const int q3 = floc & (p3 - 1);
        const int k3 = floc >> lp3;
        if (k3 >= 1 && k3 < nk3) {
          const int ch3 = wn >> lp3;
          const int i0 = q3 * ch3;
          const int ntrip = ((q3 == p3 - 1) ? wn : i0 + ch3) - i0;
          auto val = [&](int i) { return SC(k3, k3 + i) + SC(k3 + wn, k3 + 1 + i); };
          float r = lse_run(val, i0, ntrip, NEGF, false, lp3);
          if (q3 == 0) ssw[wn * S + k3] = r;
        }
      } else {               // enrich: rows split over 2^lt threads (elementwise)
        const int rows1 = nk3 - 1;
        const int rowlen = wn - 1;
        const int rlP2 = rowlen | 1;
        if (rows1 > 0 && rowlen > 0) {
          const int rows = 2 * rows1;
          int lt = 0;
          while (lt < 5 && (rows << (lt + 1)) <= 512 && (rowlen >> (lt + 1)) >= 1)
            ++lt;
          const int rowid = floc >> lt;
          const int e = floc & ((1 << lt) - 1);
          if (rowid < rows) {
            const int typ = (rowid >= rows1) ? 1 : 0;
            const int kk2 = rowid - typ * rows1;
            const int kr = kk2 + 1;
            float* st = &stage[(typ * rows1 + kk2) * rlP2];
            const int i0 = (rowlen * e) >> lt;          // balanced chunks
            const int ie = (rowlen * (e + 1)) >> lt;
            if (typ == 0) {
              // ir row k: += SSW[wn-1-i][kr+1+i] (anti-diagonal)
              const float* pw_ = ssw + (wn - 1) * S + (kr + 1);
#pragma unroll 4
              for (int i = i0; i < ie; ++i) st[i] += pw_[i * (1 - S)];
            } else {
              // il row k: += SSW[1+i][kr] (column)
              const float* pw_ = ssw + S + kr;
#pragma unroll 4
              for (int i = i0; i < ie; ++i) st[i] += pw_[i * S];
            }
          }
        }
      }
      spk_off += 2 * (S - wn - 1) * ((wn - 1) | 1);
    }
    __syncthreads();   // B3: stage(w+1) complete
  }
}

// Gather score: masked arc scores + positive-sibling scores, count mask.
__global__ __launch_bounds__(256) void score_kernel(
    const float* __restrict__ arc, const float* __restrict__ sib,
    const unsigned char* __restrict__ mask, const int* __restrict__ arcs,
    const int* __restrict__ sibs, int B)
{
  __shared__ bool bytes_sh;
  if (threadIdx.x == 0) {
    int c = 0;
    for (int i = 0; i < S; ++i) c += (mask[i] != 0);
    bytes_sh = (c >= 64);
  }
  __syncthreads();
  const bool bytes = bytes_sh;

  const int total = B * S * S;
  int tid = blockIdx.x * blockDim.x + threadIdx.x;
  float sum = 0.f, cnt = 0.f;
  for (int e = tid; e < total; e += gridDim.x * blockDim.x) {
    int sv = sibs[e];
    if (sv > 0) sum += sib[(size_t)e * S + sv];
    if ((e & (S - 1)) == 0) {           // once per (b,i)
      int bi = e >> 7;
      if (mask_at(mask, bi, bytes)) { sum += arc[(size_t)bi * S + arcs[bi]]; cnt += 1.f; }
    }
  }
  __shared__ float rs[256], rc[256];
  rs[threadIdx.x] = sum; rc[threadIdx.x] = cnt;
  __syncthreads();
  for (int off = 128; off; off >>= 1) {
    if (threadIdx.x < off) {
      rs[threadIdx.x] += rs[threadIdx.x + off];
      rc[threadIdx.x] += rc[threadIdx.x + off];
    }
    __syncthreads();
  }
  if (threadIdx.x == 0) {
    g_partials[blockIdx.x * 2]     = rs[0];
    g_partials[blockIdx.x * 2 + 1] = rc[0];
  }
}

__global__ __launch_bounds__(256) void final_kernel(int B, float* __restrict__ out)
{
  __shared__ float rs[256], rc[256];
  int t = threadIdx.x;
  float v = -g_partials[t * 2];
  float c = g_partials[t * 2 + 1];
  if (t < B) v += g_logZ[t];
  rs[t] = v; rc[t] = c;
  __syncthreads();
  for (int off = 128; off; off >>= 1) {
    if (t < off) { rs[t] += rs[t + off]; rc[t] += rc[t + off]; }
    __syncthreads();
  }
  if (t == 0) out[0] = rs[0] / rc[0];   // (logZ - score) / mask.sum()
}

extern "C" void kernel_launch(void* const* d_in, const int* in_sizes, int n_in,
                              void* d_out, int out_size, void* d_ws, size_t ws_size,
                              hipStream_t stream) {
  const float* s_arc = (const float*)d_in[0];
  const float* s_sib = (const float*)d_in[1];
  const unsigned char* mask = (const unsigned char*)d_in[2];
  const int* arcs = (const int*)d_in[3];
  const int* sibs = (const int*)d_in[4];
  int B = in_sizes[0] / (S * S);
  if (B > MAXB) B = MAXB;

  pack_kernel<<<dim3(B * 126), dim3(256), 0, stream>>>(s_sib);
  score_kernel<<<dim3(256), dim3(256), 0, stream>>>(s_arc, s_sib, mask, arcs, sibs, B);
  dp_kernel<<<dim3(B), dim3(NT), 0, stream>>>(s_arc, mask);
  final_kernel<<<dim3(1), dim3(256), 0, stream>>>(B, (float*)d_out);
}

// Round 12
// 774.775 us; speedup vs baseline: 1.2192x; 1.2192x over previous
//
#include <hip/hip_runtime.h>

#define S 128
#define NEGF (-1e30f)
#define MAXB 16
#define NT 512
#define STAGE_SZ 8064     // max over wn of 2*(S-wn-1)*((wn-1)|1)  (wn=63)
#define PKB 700000        // per-batch packed sib floats (>= 698250 exact)

// Static device workspace (d_ws proved unreliable in rounds 0-2).
__device__ float g_ssw[MAXB * S * S];        // sibling spans, [b][width][start]
__device__ float g_spk[(size_t)MAXB * PKB];  // packed sib, [b][wn][typ][k-1][i]
__device__ float g_logZ[MAXB];
__device__ float g_partials[512];

__device__ __forceinline__ bool mask_at(const unsigned char* m, int i, bool by) {
  return by ? (m[i] != 0) : (((const int*)m)[i] != 0);
}

// global -> LDS DMA, 4B/lane: dest = wave-uniform base + lane*4 (r6-r11 verified).
__device__ __forceinline__ void gload_lds4(const float* g, float* l) {
  __builtin_amdgcn_global_load_lds(
      (const __attribute__((address_space(1))) unsigned int*)g,
      (__attribute__((address_space(3))) unsigned int*)l, 4, 0, 0);
}

// Online-lse pieces (r8/r10-verified). Finite NEGF sentinel => no NaN.
__device__ __forceinline__ void upd(float& m, float& s, float v) {
  float mn = fmaxf(m, v);
  s = s * __expf(m - mn) + __expf(v - mn);
  m = mn;
}
__device__ __forceinline__ void fold(float& m0, float& s0, float m1, float s1) {
  float mn = fmaxf(m0, m1);
  s0 = s0 * __expf(m0 - mn) + s1 * __expf(m1 - mn);
  m0 = mn;
}
template <int CTRL>
__device__ __forceinline__ float dpp_f(float x) {
  int i = __float_as_int(x);
  return __int_as_float(__builtin_amdgcn_update_dpp(i, i, CTRL, 0xF, 0xF, false));
}
// Cross-lane (m,s) fold over p=2^lp lane-aligned groups (r5/r9/r10-verified
// ctrls): xor1(0xB1), xor2(0x4E), mirror8(0x141)~xor4, mirror16(0x140)~xor8.
__device__ __forceinline__ void xfold(float& m, float& s, int lp) {
  if (lp >= 1) { float mo = dpp_f<0xB1>(m),  so = dpp_f<0xB1>(s);  fold(m, s, mo, so); }
  if (lp >= 2) { float mo = dpp_f<0x4E>(m),  so = dpp_f<0x4E>(s);  fold(m, s, mo, so); }
  if (lp >= 3) { float mo = dpp_f<0x141>(m), so = dpp_f<0x141>(s); fold(m, s, mo, so); }
  if (lp >= 4) { float mo = dpp_f<0x140>(m), so = dpp_f<0x140>(s); fold(m, s, mo, so); }
}
// Chunk-8 two-pass lse: per chunk, cache 8 values in static regs (rule-#20
// safe), one max-tree, 8 exps from regs, one online chunk-fold (exp count:
// 1/elem + 2/chunk vs online-upd's 2/elem). Tail <8 elems: online upd.
template <typename F>
__device__ __forceinline__ float lse_c8(F val, int i0, int n,
                                        float base, bool has_base, int lp) {
  float M = has_base ? base : NEGF;
  float Ss = has_base ? 1.f : 0.f;
  int i = i0;
  const int ie = i0 + n;
  for (; i + 8 <= ie; i += 8) {
    float v0 = val(i),     v1 = val(i + 1), v2 = val(i + 2), v3 = val(i + 3),
          v4 = val(i + 4), v5 = val(i + 5), v6 = val(i + 6), v7 = val(i + 7);
    float mc = fmaxf(fmaxf(fmaxf(v0, v1), fmaxf(v2, v3)),
                     fmaxf(fmaxf(v4, v5), fmaxf(v6, v7)));
    float s8 = ((__expf(v0 - mc) + __expf(v1 - mc)) +
                (__expf(v2 - mc) + __expf(v3 - mc))) +
               ((__expf(v4 - mc) + __expf(v5 - mc)) +
                (__expf(v6 - mc) + __expf(v7 - mc)));
    float mn = fmaxf(M, mc);
    Ss = Ss * __expf(M - mn) + s8 * __expf(mc - mn);
    M = mn;
  }
  for (; i < ie; ++i) upd(M, Ss, val(i));
  xfold(M, Ss, lp);
  return __logf(Ss) + M;
}
__device__ __forceinline__ int lp_cap(int cap) {
  return cap >= 16 ? 4 : cap >= 8 ? 3 : cap >= 4 ? 2 : cap >= 2 ? 1 : 0;
}

// One-time repack of s_sib into the per-width stage layout (all 256 CUs):
// dst[b][OFF(wn) + (typ*(nk2-1) + (k-1))*rlP + i] = sib[b][dep][head][k+1+i]
__global__ __launch_bounds__(256) void pack_kernel(const float* __restrict__ sib) {
  const int wn = 2 + (blockIdx.x % 126);
  const int b = blockIdx.x / 126;
  const int nk2 = S - wn;
  const int rows1 = nk2 - 1;
  if (rows1 <= 0) return;
  const int rowlen = wn - 1;
  const int rlP = rowlen | 1;
  int off = 0;
  for (int v = 2; v < wn; ++v) off += 2 * (S - v - 1) * ((v - 1) | 1);
  const float* SBraw = sib + (size_t)b * S * S * S;   // [dep][head][sib]
  float* dst = g_spk + (size_t)b * PKB + off;
  const int lane5 = threadIdx.x & 31;
  const int R = 2 * rows1;
  for (int r = (threadIdx.x >> 5); r < R; r += 8) {
    const int typ = (r >= rows1) ? 1 : 0;
    const int kr = (r - typ * rows1) + 1;
    const int kw2 = kr + wn;
    const size_t srcoff = (typ == 0)
        ? ((size_t)(kw2 * S + kr) * S + (kr + 1))    // ir: sib[dep=kw][head=k][x]
        : ((size_t)(kr * S + kw2) * S + (kr + 1));   // il: sib[dep=k][head=kw][x]
    const float* src = SBraw + srcoff;
    float* d = dst + r * rlP;
    for (int i = lane5; i < rowlen; i += 32) d[i] = src[i];
  }
}

// One block (512 thr) per batch element. TWO barriers per width:
//   PH_A: ir || il || slr(w)   (3 families; slr(w) reads sc(<=w-1) only,
//         writes ssw[w] which ir/il read first at width w+1 -> disjoint)
//   B1; linear DMA stage(w+1)
//   PH_B: cl || cr
//   B2 (drains DMA)
// SSW term folded into ph1's loop (3rd read, L2-resident, k-coalesced).
__global__ __launch_bounds__(NT) void dp_kernel(
    const float* __restrict__ arc,          // [B,S,S] s_arc[b,dep,head]
    const unsigned char* __restrict__ mask) // [B,S]
{
  __shared__ float si[S][S];
  __shared__ float sc[S][S];
  __shared__ float stage[STAGE_SZ];
  __shared__ int len_sh, cnt0_sh;

  const int b = blockIdx.x;
  const int tid = threadIdx.x;
  const float* arc_b = arc + (size_t)b * S * S;      // arc_b[dep*S+head]
  const float* spk_b = g_spk + (size_t)b * PKB;
  float* ssw = g_ssw + (size_t)b * S * S;

  if (tid == 0) { len_sh = 0; cnt0_sh = 0; }
  __syncthreads();
  if (tid < S && mask[tid] != 0) atomicAdd(&cnt0_sh, 1);  // byte-interp of row 0
  for (int i = tid; i < S * S; i += NT) {
    (&si[0][0])[i] = NEGF;
    (&sc[0][0])[i] = NEGF;
  }
  __syncthreads();
  const bool bytes = (cnt0_sh >= 64);  // bool bytes: ~127 nonzero; int32: ~31
  if (tid < S) {
    sc[tid][tid] = 0.0f;               // width-0 complete spans
    if (mask_at(mask, b * S + tid, bytes)) atomicAdd(&len_sh, 1);
  }
  __syncthreads();
  const int len = min(len_sh, S - 1);
  if (tid == 0) g_logZ[b] = 0.0f;      // len==0 fallback

  int spk_off = 0;                     // running OFF(wn), wn = w+1

  for (int w = 1; w < S; ++w) {
    const int nk = S - w, n1 = w - 1;
    const int rlP = n1 | 1;

    // ========== PH_A: ir || il || slr(w)  (T = 3*nk tasks) ==========
    {
      const int T = 3 * nk;
      const int lp = lp_cap(NT / T);
      const int p = 1 << lp;
      const int q = tid & (p - 1);
      const int t = tid >> lp;
      if (t < T) {
        const int typ = (t < nk) ? 0 : ((t < 2 * nk) ? 1 : 2);
        const int k = t - typ * nk;
        const int kw = k + w;
        if (typ < 2) {
          float bm, arcv;
          const float *pa, *pt, *pw;
          int wstr;
          if (typ == 0) {      // I(k -> kw): base j=0; siblings x=k+1..kw-1
            bm = sc[k][k] + sc[kw][k + 1];
            arcv = arc_b[kw * S + k];
            pa = &si[k][k + 1];
            pt = &stage[(k >= 1 ? k - 1 : 0) * rlP];
            pw = ssw + (w - 1) * S + (k + 1);   // SSW[w-1-i][k+1+i]
            wstr = 1 - S;
          } else {             // I(kw -> k): base j=w-1; siblings x=k+1..kw-1
            bm = (k == 0) ? 0.0f : (sc[kw][kw] + sc[k][kw - 1]);
            arcv = arc_b[k * S + kw];
            pa = &si[kw][k + 1];
            pt = &stage[((nk - 1) + (k >= 1 ? k - 1 : 0)) * rlP];
            pw = ssw + S + k;                   // SSW[1+i][k]
            wstr = S;
          }
          int i0 = 0, n = 0;
          if (k >= 1 && n1 > 0) {
            const int ch = n1 >> lp;
            i0 = q * ch;
            n = ((q == p - 1) ? n1 : i0 + ch) - i0;
          }
          auto val = [&](int i) { return pa[i] + pt[i] + pw[i * wstr]; };
          float r = lse_c8(val, i0, n, bm, q == 0, lp) + arcv;
          if (q == 0) {
            if (typ == 0) si[k][kw] = r; else si[kw][k] = r;
          }
        } else if (k >= 1) {   // slr: S(k, k+w) over x=k..kw-1 (w elems)
          const float* ra = &sc[k][k];        // C(k -> k+i)   row, contig
          const float* rb = &sc[kw][k + 1];   // C(kw -> k+1+i) row, contig
          const int ch = w >> lp;
          const int i0 = q * ch;
          const int n = ((q == p - 1) ? w : i0 + ch) - i0;
          auto val = [&](int i) { return ra[i] + rb[i]; };
          float r = lse_c8(val, i0, n, NEGF, false, lp);
          if (q == 0) ssw[w * S + k] = r;
        }
      }
    }
    __syncthreads();   // B1: si(w)/ssw(w) final; stage(w) dead

    // ===== linear DMA: packed sib block for width w+1 (drains at B2) =====
    const int wn = w + 1;
    if (wn < S) {
      const int rows1n = S - wn - 1;
      const int T = 2 * rows1n * ((wn - 1) | 1);
      const float* src = spk_b + spk_off;
      const int wv = tid >> 6, l = tid & 63;
      for (int c = wv; c * 64 < T; c += 8) {
        const int e = c * 64 + l;
        if (e < T) gload_lds4(src + e, &stage[c * 64]);
      }
      spk_off += T;
    }

    // ========== PH_B: cl || cr  (T2 = 2*nk tasks) ==========
    {
      const int lp = lp_cap(NT / (2 * nk));
      const int p = 1 << lp;
      const int q = tid & (p - 1);
      const int t = tid >> lp;
      if (t < 2 * nk) {
        const int typ = (t < nk) ? 0 : 1;
        const int k = t - typ * nk;
        const int kw = k + w;
        const int ch = w >> lp;
        const int i0 = q * ch;
        const int n = ((q == p - 1) ? w : i0 + ch) - i0;
        if (typ == 0) {      // cl: C(kw->k) over x=0..w-1: sc[k+x][k]+si[kw][k+x]
          const float* pA = &sc[k][k];      // pA[i*S] = sc[k+i][k]  (bank k)
          const float* pB = &si[kw][k];
          auto val = [&](int i) { return pA[i * S] + pB[i]; };
          float r = lse_c8(val, i0, n, NEGF, false, lp);
          if (q == 0) sc[kw][k] = r;
        } else {             // cr: C(k->kw) over y=1..w: si[k][k+y]+sc[k+y][kw]
          const float* pA = &si[k][k + 1];
          const float* pB = &sc[k + 1][kw]; // pB[i*S] = sc[k+1+i][kw]
          auto val = [&](int i) { return pA[i] + pB[i * S]; };
          float r = lse_c8(val, i0, n, NEGF, false, lp);
          if (q == 0) {
            if (k == 0) {
              // single-root kill: C(0->w) survives only at w == len
              if (w == len) g_logZ[b] = r;
              sc[0][w] = (w == len) ? r : NEGF;
            } else {
              sc[k][kw] = r;
            }
          }
        }
      }
    }
    __syncthreads();   // B2: sc(w) final; DMA(w+1) landed
  }
}

// Gather score: masked arc scores + positive-sibling scores, count mask.
__global__ __launch_bounds__(256) void score_kernel(
    const float* __restrict__ arc, const float* __restrict__ sib,
    const unsigned char* __restrict__ mask, const int* __restrict__ arcs,
    const int* __restrict__ sibs, int B)
{
  __shared__ bool bytes_sh;
  if (threadIdx.x == 0) {
    int c = 0;
    for (int i = 0; i < S; ++i) c += (mask[i] != 0);
    bytes_sh = (c >= 64);
  }
  __syncthreads();
  const bool bytes = bytes_sh;

  const int total = B * S * S;
  int tid = blockIdx.x * blockDim.x + threadIdx.x;
  float sum = 0.f, cnt = 0.f;
  for (int e = tid; e < total; e += gridDim.x * blockDim.x) {
    int sv = sibs[e];
    if (sv > 0) sum += sib[(size_t)e * S + sv];
    if ((e & (S - 1)) == 0) {           // once per (b,i)
      int bi = e >> 7;
      if (mask_at(mask, bi, bytes)) { sum += arc[(size_t)bi * S + arcs[bi]]; cnt += 1.f; }
    }
  }
  __shared__ float rs[256], rc[256];
  rs[threadIdx.x] = sum; rc[threadIdx.x] = cnt;
  __syncthreads();
  for (int off = 128; off; off >>= 1) {
    if (threadIdx.x < off) {
      rs[threadIdx.x] += rs[threadIdx.x + off];
      rc[threadIdx.x] += rc[threadIdx.x + off];
    }
    __syncthreads();
  }
  if (threadIdx.x == 0) {
    g_partials[blockIdx.x * 2]     = rs[0];
    g_partials[blockIdx.x * 2 + 1] = rc[0];
  }
}

__global__ __launch_bounds__(256) void final_kernel(int B, float* __restrict__ out)
{
  __shared__ float rs[256], rc[256];
  int t = threadIdx.x;
  float v = -g_partials[t * 2];
  float c = g_partials[t * 2 + 1];
  if (t < B) v += g_logZ[t];
  rs[t] = v; rc[t] = c;
  __syncthreads();
  for (int off = 128; off; off >>= 1) {
    if (t < off) { rs[t] += rs[t + off]; rc[t] += rc[t + off]; }
    __syncthreads();
  }
  if (t == 0) out[0] = rs[0] / rc[0];   // (logZ - score) / mask.sum()
}

extern "C" void kernel_launch(void* const* d_in, const int* in_sizes, int n_in,
                              void* d_out, int out_size, void* d_ws, size_t ws_size,
                              hipStream_t stream) {
  const float* s_arc = (const float*)d_in[0];
  const float* s_sib = (const float*)d_in[1];
  const unsigned char* mask = (const unsigned char*)d_in[2];
  const int* arcs = (const int*)d_in[3];
  const int* sibs = (const int*)d_in[4];
  int B = in_sizes[0] / (S * S);
  if (B > MAXB) B = MAXB;

  pack_kernel<<<dim3(B * 126), dim3(256), 0, stream>>>(s_sib);
  score_kernel<<<dim3(256), dim3(256), 0, stream>>>(s_arc, s_sib, mask, arcs, sibs, B);
  dp_kernel<<<dim3(B), dim3(NT), 0, stream>>>(s_arc, mask);
  final_kernel<<<dim3(1), dim3(256), 0, stream>>>(B, (float*)d_out);
}

// Round 13
// 547.327 us; speedup vs baseline: 1.7259x; 1.4156x over previous
//
#include <hip/hip_runtime.h>

#define S 128
#define NEGF (-1e30f)
#define MAXB 16
#define NT 1024
#define STAGE_SZ 8064     // max over wn of 2*(S-wn-1)*((wn-1)|1)  (wn=63)
#define PKB 700000        // per-batch packed sib floats (>= 698250 exact)

// Static device workspace (d_ws proved unreliable in rounds 0-2).
__device__ float g_ssw[MAXB * S * S];        // sibling spans, [b][width][start]
__device__ float g_spk[(size_t)MAXB * PKB];  // packed sib, [b][wn][typ][k-1][i]
__device__ float g_logZ[MAXB];
__device__ float g_partials[512];

__device__ __forceinline__ bool mask_at(const unsigned char* m, int i, bool by) {
  return by ? (m[i] != 0) : (((const int*)m)[i] != 0);
}

// global -> LDS DMA, 4B/lane: dest = wave-uniform base + lane*4 (r6-r12 verified).
__device__ __forceinline__ void gload_lds4(const float* g, float* l) {
  __builtin_amdgcn_global_load_lds(
      (const __attribute__((address_space(1))) unsigned int*)g,
      (__attribute__((address_space(3))) unsigned int*)l, 4, 0, 0);
}

// Online-lse pieces (r8-r12 verified). Finite NEGF sentinel => no NaN.
__device__ __forceinline__ void upd(float& m, float& s, float v) {
  float mn = fmaxf(m, v);
  s = s * __expf(m - mn) + __expf(v - mn);
  m = mn;
}
__device__ __forceinline__ void fold(float& m0, float& s0, float m1, float s1) {
  float mn = fmaxf(m0, m1);
  s0 = s0 * __expf(m0 - mn) + s1 * __expf(m1 - mn);
  m0 = mn;
}
template <int CTRL>
__device__ __forceinline__ float dpp_f(float x) {
  int i = __float_as_int(x);
  return __int_as_float(__builtin_amdgcn_update_dpp(i, i, CTRL, 0xF, 0xF, false));
}
// Cross-lane (m,s) fold over p=2^lp lane-aligned groups (r5-r12 verified
// ctrls): xor1(0xB1), xor2(0x4E), mirror8(0x141)~xor4, mirror16(0x140)~xor8.
__device__ __forceinline__ void xfold(float& m, float& s, int lp) {
  if (lp >= 1) { float mo = dpp_f<0xB1>(m),  so = dpp_f<0xB1>(s);  fold(m, s, mo, so); }
  if (lp >= 2) { float mo = dpp_f<0x4E>(m),  so = dpp_f<0x4E>(s);  fold(m, s, mo, so); }
  if (lp >= 3) { float mo = dpp_f<0x141>(m), so = dpp_f<0x141>(s); fold(m, s, mo, so); }
  if (lp >= 4) { float mo = dpp_f<0x140>(m), so = dpp_f<0x140>(s); fold(m, s, mo, so); }
}
// Chunk-8 accumulate (r12-verified body): caches 8 vals in static regs,
// one max-tree, 8 exps, one chunk-fold; tail online.
template <typename F>
__device__ __forceinline__ void lse_acc(F val, int i0, int n, float& M, float& Ss) {
  int i = i0;
  const int ie = i0 + n;
  for (; i + 8 <= ie; i += 8) {
    float v0 = val(i),     v1 = val(i + 1), v2 = val(i + 2), v3 = val(i + 3),
          v4 = val(i + 4), v5 = val(i + 5), v6 = val(i + 6), v7 = val(i + 7);
    float mc = fmaxf(fmaxf(fmaxf(v0, v1), fmaxf(v2, v3)),
                     fmaxf(fmaxf(v4, v5), fmaxf(v6, v7)));
    float s8 = ((__expf(v0 - mc) + __expf(v1 - mc)) +
                (__expf(v2 - mc) + __expf(v3 - mc))) +
               ((__expf(v4 - mc) + __expf(v5 - mc)) +
                (__expf(v6 - mc) + __expf(v7 - mc)));
    float mn = fmaxf(M, mc);
    Ss = Ss * __expf(M - mn) + s8 * __expf(mc - mn);
    M = mn;
  }
  for (; i < ie; ++i) upd(M, Ss, val(i));
}
template <typename F>
__device__ __forceinline__ float lse_c8(F val, int i0, int n, int lp) {
  float M = NEGF, Ss = 0.f;
  lse_acc(val, i0, n, M, Ss);
  xfold(M, Ss, lp);
  return __logf(Ss) + M;
}
__device__ __forceinline__ int lp_cap(int cap) {
  return cap >= 16 ? 4 : cap >= 8 ? 3 : cap >= 4 ? 2 : cap >= 2 ? 1 : 0;
}

// One-time repack of s_sib into the per-width stage layout (all 256 CUs).
__global__ __launch_bounds__(256) void pack_kernel(const float* __restrict__ sib) {
  const int wn = 2 + (blockIdx.x % 126);
  const int b = blockIdx.x / 126;
  const int nk2 = S - wn;
  const int rows1 = nk2 - 1;
  if (rows1 <= 0) return;
  const int rowlen = wn - 1;
  const int rlP = rowlen | 1;
  int off = 0;
  for (int v = 2; v < wn; ++v) off += 2 * (S - v - 1) * ((v - 1) | 1);
  const float* SBraw = sib + (size_t)b * S * S * S;   // [dep][head][sib]
  float* dst = g_spk + (size_t)b * PKB + off;
  const int lane5 = threadIdx.x & 31;
  const int R = 2 * rows1;
  for (int r = (threadIdx.x >> 5); r < R; r += 8) {
    const int typ = (r >= rows1) ? 1 : 0;
    const int kr = (r - typ * rows1) + 1;
    const int kw2 = kr + wn;
    const size_t srcoff = (typ == 0)
        ? ((size_t)(kw2 * S + kr) * S + (kr + 1))    // ir: sib[dep=kw][head=k][x]
        : ((size_t)(kr * S + kw2) * S + (kr + 1));   // il: sib[dep=k][head=kw][x]
    const float* src = SBraw + srcoff;
    float* d = dst + r * rlP;
    for (int i = lane5; i < rowlen; i += 32) d[i] = src[i];
  }
}

// One block (1024 thr = 16 waves) per batch element. Software-pipelined:
// the serial sibling-lse of ir/il(w+1) runs DURING PH_B(w) (it needs only
// si(<=w), ssw(<=w), staged sib -- not sc(w)); its (m,s) partial is carried
// in registers across the barrier. PH_A(w) just folds the base term in.
// Per width w (2 barriers):
//   [issue DMA(w+1)]
//   PH_A: slr(w) [tid<512, p<=16] || finish ir/il(w) from partials [tid>=512]
//   B1 (si(w), ssw(w) final; DMA(w+1) landed)
//   PH_B: cl(w) [0,256) || cr(w) [256,512) || partial-ir(w+1) [512,768)
//         || partial-il(w+1) [768,1024)
//   B2 (sc(w) final)
__global__ __launch_bounds__(NT) void dp_kernel(
    const float* __restrict__ arc,          // [B,S,S] s_arc[b,dep,head]
    const unsigned char* __restrict__ mask) // [B,S]
{
  __shared__ float si[S][S];
  __shared__ float sc[S][S];
  __shared__ float stage[STAGE_SZ];
  __shared__ int len_sh, cnt0_sh;

  const int b = blockIdx.x;
  const int tid = threadIdx.x;
  const float* arc_b = arc + (size_t)b * S * S;      // arc_b[dep*S+head]
  const float* spk_b = g_spk + (size_t)b * PKB;
  float* ssw = g_ssw + (size_t)b * S * S;

  if (tid == 0) { len_sh = 0; cnt0_sh = 0; }
  __syncthreads();
  if (tid < S && mask[tid] != 0) atomicAdd(&cnt0_sh, 1);  // byte-interp of row 0
  for (int i = tid; i < S * S; i += NT) {
    (&si[0][0])[i] = NEGF;
    (&sc[0][0])[i] = NEGF;
  }
  __syncthreads();
  const bool bytes = (cnt0_sh >= 64);  // bool bytes: ~127 nonzero; int32: ~31
  if (tid < S) {
    sc[tid][tid] = 0.0f;               // width-0 complete spans
    if (mask_at(mask, b * S + tid, bytes)) atomicAdd(&len_sh, 1);
  }
  __syncthreads();
  const int len = min(len_sh, S - 1);
  if (tid == 0) g_logZ[b] = 0.0f;      // len==0 fallback

  // Persistent pipeline registers (meaningful for tid >= 512 only):
  float mP = NEGF, sP = 0.f, arcvP = 0.f;
  // Prologue: prefetch arc for the w=1 finish (w=1 has no sibling partial).
  if (tid >= 512) {
    const int fam = (tid >= 768);
    const int floc = tid & 255;
    const int lp = lp_cap(256 / (S - 1));
    const int k = floc >> lp;
    if (k < S - 1)
      arcvP = fam ? arc_b[k * S + (k + 1)] : arc_b[(k + 1) * S + k];
  }

  int spk_off = 0;                     // running OFF(wn), wn = w+1

  for (int w = 1; w < S; ++w) {
    const int nk = S - w;
    const int wn = w + 1;

    // ===== issue DMA(w+1): stage(w) was last read in PH_B(w-1) =====
    if (wn < S) {
      const int rows1n = S - wn - 1;
      const int T = 2 * rows1n * ((wn - 1) | 1);
      const float* src = spk_b + spk_off;
      const int wv = tid >> 6, l = tid & 63;
      for (int c = wv; c * 64 < T; c += 16) {
        const int e = c * 64 + l;
        if (e < T) gload_lds4(src + e, &stage[c * 64]);
      }
      spk_off += T;
    }

    // ========== PH_A: slr(w) || finish ir/il(w) ==========
    if (tid < 512) {                   // slr: S(k, k+w), k in [1, nk)
      const int lp = lp_cap(512 / nk);
      const int p = 1 << lp;
      const int q = tid & (p - 1);
      const int k = tid >> lp;
      if (k >= 1 && k < nk) {
        const int kw = k + w;
        const float* ra = &sc[k][k];        // C(k -> k+i)    row, contig
        const float* rb = &sc[kw][k + 1];   // C(kw -> k+1+i) row, contig
        const int ch = w >> lp;
        const int i0 = q * ch;
        const int n = ((q == p - 1) ? w : i0 + ch) - i0;
        auto val = [&](int i) { return ra[i] + rb[i]; };
        float r = lse_c8(val, i0, n, lp);
        if (q == 0) ssw[w * S + k] = r;
      }
    } else {                           // finish ir/il(w) from (mP, sP)
      const int fam = (tid >= 768);    // 0 = ir, 1 = il
      const int floc = tid & 255;
      const int lp = lp_cap(256 / nk); // same lp the partial used
      const int p = 1 << lp;
      const int q = floc & (p - 1);
      const int k = floc >> lp;
      if (k < nk) {
        const int kw = k + w;
        float bm;
        if (fam == 0) bm = sc[k][k] + sc[kw][k + 1];                // j=0 base
        else bm = (k == 0) ? 0.0f : (sc[kw][kw] + sc[k][kw - 1]);   // j=w-1 base
        float m = mP, s = sP;
        if (q == 0) fold(m, s, bm, 1.0f);
        xfold(m, s, lp);
        if (q == 0) {
          const float r = __logf(s) + m + arcvP;
          if (fam == 0) si[k][kw] = r;
          else          si[kw][k] = r;
        }
      }
    }
    __syncthreads();   // B1: si(w)/ssw(w) final; DMA(w+1) landed

    // ========== PH_B: cl || cr || partial-ir(w+1) || partial-il(w+1) ======
    if (tid < 512) {
      const int fam = (tid >= 256);    // 0 = cl, 1 = cr
      const int floc = tid & 255;
      const int lp = lp_cap(256 / nk);
      const int p = 1 << lp;
      const int q = floc & (p - 1);
      const int k = floc >> lp;
      if (k < nk) {
        const int kw = k + w;
        const int ch = w >> lp;
        const int i0 = q * ch;
        const int n = ((q == p - 1) ? w : i0 + ch) - i0;
        if (fam == 0) {      // cl: C(kw->k) over x=0..w-1: sc[k+x][k]+si[kw][k+x]
          const float* pA = &sc[k][k];      // pA[i*S] = sc[k+i][k]  (bank k)
          const float* pB = &si[kw][k];
          auto val = [&](int i) { return pA[i * S] + pB[i]; };
          float r = lse_c8(val, i0, n, lp);
          if (q == 0) sc[kw][k] = r;
        } else {             // cr: C(k->kw) over y=1..w: si[k][k+y]+sc[k+y][kw]
          const float* pA = &si[k][k + 1];
          const float* pB = &sc[k + 1][kw]; // pB[i*S] = sc[k+1+i][kw]
          auto val = [&](int i) { return pA[i] + pB[i * S]; };
          float r = lse_c8(val, i0, n, lp);
          if (q == 0) {
            if (k == 0) {
              // single-root kill: C(0->w) survives only at w == len
              if (w == len) g_logZ[b] = r;
              sc[0][w] = (w == len) ? r : NEGF;
            } else {
              sc[k][kw] = r;
            }
          }
        }
      }
    } else {
      // partial sibling-lse for ir/il(w+1); reads si(<=w), ssw(<=w), stage.
      mP = NEGF; sP = 0.f; arcvP = 0.f;
      if (wn < S) {
        const int fam = (tid >= 768);  // 0 = ir, 1 = il
        const int floc = tid & 255;
        const int nk2 = S - wn;
        const int lp = lp_cap(256 / nk2);
        const int p = 1 << lp;
        const int q = floc & (p - 1);
        const int k = floc >> lp;
        if (k < nk2) {
          const int kw2 = k + wn;
          // arc prefetch for next phase's finish (latency hidden here)
          arcvP = (fam == 0) ? arc_b[kw2 * S + k] : arc_b[k * S + kw2];
          if (k >= 1) {
            const int n1n = wn - 1;    // sibling count = w
            const int rlPn = n1n | 1;
            const float *pa, *pt, *pw;
            int wstr;
            if (fam == 0) {            // ir(k -> kw2): siblings x=k+1..kw2-1
              pa = &si[k][k + 1];
              pt = &stage[(k - 1) * rlPn];
              pw = ssw + n1n * S + (k + 1);   // SSW[wn-1-i][k+1+i]
              wstr = 1 - S;
            } else {                   // il(kw2 -> k): siblings x=k+1..kw2-1
              pa = &si[kw2][k + 1];
              pt = &stage[((nk2 - 1) + (k - 1)) * rlPn];
              pw = ssw + S + k;               // SSW[1+i][k]
              wstr = S;
            }
            const int ch = n1n >> lp;
            const int i0 = q * ch;
            const int n = ((q == p - 1) ? n1n : i0 + ch) - i0;
            auto val = [&](int i) { return pa[i] + pt[i] + pw[i * wstr]; };
            lse_acc(val, i0, n, mP, sP);
          }
        }
      }
    }
    __syncthreads();   // B2: sc(w) final
  }
}

// Gather score: masked arc scores + positive-sibling scores, count mask.
__global__ __launch_bounds__(256) void score_kernel(
    const float* __restrict__ arc, const float* __restrict__ sib,
    const unsigned char* __restrict__ mask, const int* __restrict__ arcs,
    const int* __restrict__ sibs, int B)
{
  __shared__ bool bytes_sh;
  if (threadIdx.x == 0) {
    int c = 0;
    for (int i = 0; i < S; ++i) c += (mask[i] != 0);
    bytes_sh = (c >= 64);
  }
  __syncthreads();
  const bool bytes = bytes_sh;

  const int total = B * S * S;
  int tid = blockIdx.x * blockDim.x + threadIdx.x;
  float sum = 0.f, cnt = 0.f;
  for (int e = tid; e < total; e += gridDim.x * blockDim.x) {
    int sv = sibs[e];
    if (sv > 0) sum += sib[(size_t)e * S + sv];
    if ((e & (S - 1)) == 0) {           // once per (b,i)
      int bi = e >> 7;
      if (mask_at(mask, bi, bytes)) { sum += arc[(size_t)bi * S + arcs[bi]]; cnt += 1.f; }
    }
  }
  __shared__ float rs[256], rc[256];
  rs[threadIdx.x] = sum; rc[threadIdx.x] = cnt;
  __syncthreads();
  for (int off = 128; off; off >>= 1) {
    if (threadIdx.x < off) {
      rs[threadIdx.x] += rs[threadIdx.x + off];
      rc[threadIdx.x] += rc[threadIdx.x + off];
    }
    __syncthreads();
  }
  if (threadIdx.x == 0) {
    g_partials[blockIdx.x * 2]     = rs[0];
    g_partials[blockIdx.x * 2 + 1] = rc[0];
  }
}

__global__ __launch_bounds__(256) void final_kernel(int B, float* __restrict__ out)
{
  __shared__ float rs[256], rc[256];
  int t = threadIdx.x;
  float v = -g_partials[t * 2];
  float c = g_partials[t * 2 + 1];
  if (t < B) v += g_logZ[t];
  rs[t] = v; rc[t] = c;
  __syncthreads();
  for (int off = 128; off; off >>= 1) {
    if (t < off) { rs[t] += rs[t + off]; rc[t] += rc[t + off]; }
    __syncthreads();
  }
  if (t == 0) out[0] = rs[0] / rc[0];   // (logZ - score) / mask.sum()
}

extern "C" void kernel_launch(void* const* d_in, const int* in_sizes, int n_in,
                              void* d_out, int out_size, void* d_ws, size_t ws_size,
                              hipStream_t stream) {
  const float* s_arc = (const float*)d_in[0];
  const float* s_sib = (const float*)d_in[1];
  const unsigned char* mask = (const unsigned char*)d_in[2];
  const int* arcs = (const int*)d_in[3];
  const int* sibs = (const int*)d_in[4];
  int B = in_sizes[0] / (S * S);
  if (B > MAXB) B = MAXB;

  pack_kernel<<<dim3(B * 126), dim3(256), 0, stream>>>(s_sib);
  score_kernel<<<dim3(256), dim3(256), 0, stream>>>(s_arc, s_sib, mask, arcs, sibs, B);
  dp_kernel<<<dim3(B), dim3(NT), 0, stream>>>(s_arc, mask);
  final_kernel<<<dim3(1), dim3(256), 0, stream>>>(B, (float*)d_out);
}